// Round 2
// baseline (641.099 us; speedup 1.0000x reference)
//
#include <hip/hip_runtime.h>
#include <stdint.h>

// Match reference numerics: no FMA contraction anywhere (discrete IoU>thres
// decisions flip on 1-ulp differences).
#pragma clang fp contract(off)

#define BATCH 32
#define NPRED 25200
#define ROWF 9
#define TOPK 1000
#define SUBS 8
#define ROWS_PER_SUB (NPRED / SUBS)   // 3150
#define SUBCAP 1024
#define CAP 4096
#define CONF_T 0.7f
#define IOU_T 0.45f
#define KW 16   // 1000 bits -> 16 u64 words

typedef unsigned long long u64;
typedef unsigned int u32;

// K1: compact valid candidates per (image, sub-range) into private sub-buffers.
// key = (float_bits(conf) << 32) | ~row  -> sorting keys descending gives
// (score desc, index asc) exactly matching jax.lax.top_k tie-breaking.
__global__ __launch_bounds__(256) void compact_kernel(const float* __restrict__ pred,
                                                      u32* __restrict__ counts,
                                                      u64* __restrict__ cand) {
    __shared__ u32 cnt;
    __shared__ u64 buf[SUBCAP];
    int bs = blockIdx.x;          // 0..255
    int b = bs >> 3, s = bs & 7;
    if (threadIdx.x == 0) cnt = 0;
    __syncthreads();
    int r0 = s * ROWS_PER_SUB;
    for (int r = r0 + (int)threadIdx.x; r < r0 + ROWS_PER_SUB; r += 256) {
        size_t base = ((size_t)b * NPRED + r) * ROWF;
        float obj = pred[base + 4];
        float cls = pred[base + 5];
        float conf = obj * cls;
        if (obj > CONF_T && conf > CONF_T) {
            u32 slot = atomicAdd(&cnt, 1u);
            if (slot < SUBCAP) {
                u64 key = ((u64)__float_as_uint(conf) << 32) | (u64)(u32)(~(u32)r);
                buf[slot] = key;
            }
        }
    }
    __syncthreads();
    u32 c = cnt < SUBCAP ? cnt : SUBCAP;
    if (threadIdx.x == 0) counts[bs] = c;
    for (u32 t = threadIdx.x; t < c; t += 256) cand[(size_t)bs * SUBCAP + t] = buf[t];
}

// K2: per-image: gather candidates -> bitonic sort -> top-1000 gather ->
// suppression bit-matrix -> single-wave greedy scan -> write output.
__global__ __launch_bounds__(1024) void nms_kernel(const float* __restrict__ pred,
                                                   const u32* __restrict__ counts,
                                                   const u64* __restrict__ candg,
                                                   float* __restrict__ out,      // [B,1000,9]
                                                   float* __restrict__ keepout)  // [B,1000]
{
    __shared__ u64 sup[TOPK * KW];      // 128000 B; first CAP entries alias sort buffer
    __shared__ float4 boxes_s[TOPK];    // 16000 B
    __shared__ float  area_s[TOPK];     // 4000 B
    __shared__ float  scores_s[TOPK];   // 4000 B
    __shared__ u64 kw[KW];              // 128 B

    u64* cand = sup;                    // alias: sort buffer lives where sup will go
    int b = blockIdx.x;
    int tid = threadIdx.x;

    if (tid < KW) kw[tid] = 0;
    for (int t = tid; t < CAP; t += 1024) cand[t] = 0;
    __syncthreads();

    // gather sub-buffers (order across subs arbitrary; sort fixes it)
    u32 off = 0;
    for (int s = 0; s < SUBS; ++s) {
        u32 c = counts[b * SUBS + s];
        if (c > SUBCAP) c = SUBCAP;
        u32 lim = (off + c > CAP) ? (CAP - off) : c;
        for (u32 t = tid; t < lim; t += 1024)
            cand[off + t] = candg[(size_t)(b * SUBS + s) * SUBCAP + t];
        off += lim;
    }
    __syncthreads();

    // bitonic sort, descending, CAP elements (zeros pad to the end)
    for (int k = 2; k <= CAP; k <<= 1) {
        for (int j = k >> 1; j > 0; j >>= 1) {
            for (int t = tid; t < CAP; t += 1024) {
                int p = t ^ j;
                if (p > t) {
                    u64 a = cand[t], c2 = cand[p];
                    bool desc = ((t & k) == 0);
                    if (desc ? (a < c2) : (a > c2)) { cand[t] = c2; cand[p] = a; }
                }
            }
            __syncthreads();
        }
    }

    // phase C: top-1000 unpack + gather pred rows + compute boxes
    float sc = 0.f, a6 = 0.f, a7 = 0.f, a8 = 0.f;
    float4 box = make_float4(0.f, 0.f, 0.f, 0.f);
    if (tid < TOPK) {
        u64 key = cand[tid];
        if (key != 0) {
            sc = __uint_as_float((u32)(key >> 32));
            u32 r = ~(u32)key;
            const float* p = pred + ((size_t)b * NPRED + r) * ROWF;
            float x = p[0], y = p[1], w = p[2], h = p[3];
            box = make_float4(x - w * 0.5f, y - h * 0.5f, x + w * 0.5f, y + h * 0.5f);
            a6 = p[6]; a7 = p[7]; a8 = p[8];
            atomicOr(&kw[tid >> 6], 1ull << (tid & 63));
        }
        boxes_s[tid] = box;
        area_s[tid] = (box.z - box.x) * (box.w - box.y);
        scores_s[tid] = sc;
    }
    __syncthreads();   // cand reads done + boxes visible before sup overwrite

    // phase D: suppression matrix sup[i][word] (bits only for j > i)
    for (int task = tid; task < TOPK * KW; task += 1024) {
        int i = task >> 4, wd = task & 15;
        int j0 = wd << 6;
        u64 m = 0;
        if (j0 + 63 > i) {
            float4 bi = boxes_s[i];
            float ai = area_s[i];
            int js = (j0 > i + 1) ? j0 : i + 1;
            int je = (j0 + 64 < TOPK) ? (j0 + 64) : TOPK;
            for (int j = js; j < je; ++j) {
                float4 bj = boxes_s[j];
                float lx = fmaxf(bi.x, bj.x);
                float ly = fmaxf(bi.y, bj.y);
                float rx = fminf(bi.z, bj.z);
                float ry = fminf(bi.w, bj.w);
                float iw = rx - lx; iw = iw > 0.f ? iw : 0.f;
                float ih = ry - ly; ih = ih > 0.f ? ih : 0.f;
                float inter = iw * ih;
                float den = ai + area_s[j] - inter + 1e-7f;  // ((ai+aj)-inter)+eps, ref order
                float iou = inter / den;
                if (iou > IOU_T) m |= 1ull << (j - j0);
            }
        }
        sup[task] = m;
    }
    __syncthreads();

    // phase E: greedy scan, wave 0 only; skip-ahead over surviving bits.
    if (tid < 64) {
        u64 keepw = (tid < KW) ? kw[tid] : 0ull;
        int i = -1;
        while (true) {
            u64 cb = keepw;
            if (i >= 0) {
                int iw_ = i >> 6;
                int ib = i & 63;
                if (tid < iw_) cb = 0;
                else if (tid == iw_) cb &= (ib == 63) ? 0ull : (~0ull << (ib + 1));
            }
            u64 bal = __ballot(cb != 0);
            if (bal == 0) break;
            int f = __ffsll(bal) - 1;
            u64 wsel = __shfl(cb, f);
            int bb = __ffsll(wsel) - 1;
            i = f * 64 + bb;            // next still-kept box; it is a final survivor
            if (tid < KW) keepw &= ~sup[i * KW + tid];
        }
        if (tid < KW) kw[tid] = keepw;
    }
    __syncthreads();

    // phase F: write output rows + keep mask
    if (tid < TOPK) {
        bool kp = (kw[tid >> 6] >> (tid & 63)) & 1ull;
        size_t ob = ((size_t)b * TOPK + tid) * ROWF;
        float4 bx = boxes_s[tid];
        out[ob + 0] = kp ? bx.x : 0.f;
        out[ob + 1] = kp ? bx.y : 0.f;
        out[ob + 2] = kp ? bx.z : 0.f;
        out[ob + 3] = kp ? bx.w : 0.f;
        out[ob + 4] = kp ? scores_s[tid] : 0.f;
        out[ob + 5] = 0.f;
        out[ob + 6] = kp ? a6 : 0.f;
        out[ob + 7] = kp ? a7 : 0.f;
        out[ob + 8] = kp ? a8 : 0.f;
        keepout[(size_t)b * TOPK + tid] = kp ? 1.0f : 0.0f;
    }
}

extern "C" void kernel_launch(void* const* d_in, const int* in_sizes, int n_in,
                              void* d_out, int out_size, void* d_ws, size_t ws_size,
                              hipStream_t stream) {
    const float* pred = (const float*)d_in[0];
    float* out = (float*)d_out;                         // [32,1000,9]
    float* keepout = out + (size_t)BATCH * TOPK * ROWF; // [32,1000]
    u32* counts = (u32*)d_ws;                           // 256 u32
    u64* cand = (u64*)((char*)d_ws + 2048);             // 256*1024 u64 = 2 MB

    compact_kernel<<<BATCH * SUBS, 256, 0, stream>>>(pred, counts, cand);
    nms_kernel<<<BATCH, 1024, 0, stream>>>(pred, counts, cand, out, keepout);
}

// Round 3
// 494.936 us; speedup vs baseline: 1.2953x; 1.2953x over previous
//
#include <hip/hip_runtime.h>
#include <stdint.h>

// Match reference numerics: no FMA contraction anywhere (discrete IoU>thres
// decisions flip on 1-ulp differences).
#pragma clang fp contract(off)

#define BATCH 32
#define NPRED 25200
#define ROWF 9
#define TOPK 1000
#define SUBS 8
#define ROWS_PER_SUB (NPRED / SUBS)   // 3150
#define SUBCAP 1024
#define CAP 4096
#define CONF_T 0.7f
#define IOU_T 0.45f
#define KW 16          // 1000 bits -> 16 u64 words
#define SUPSTRIDE 1001 // column-major sup stride: (2*1001*wd)%32=18*wd -> 16 distinct banks

typedef unsigned long long u64;
typedef unsigned int u32;

// K1: compact valid candidates per (image, sub-range) into private sub-buffers.
// Stages full rows through LDS so global loads are contiguous/coalesced.
// key = (float_bits(conf) << 32) | ~row -> descending sort == (score desc, idx asc),
// exactly jax.lax.top_k tie-breaking.
__global__ __launch_bounds__(512) void compact_kernel(const float* __restrict__ pred,
                                                      u32* __restrict__ counts,
                                                      u64* __restrict__ cand) {
    __shared__ float stage[512 * ROWF];   // 18432 B
    __shared__ u64 buf[SUBCAP];           // 8192 B
    __shared__ u32 cnt;
    int bs = blockIdx.x;          // 0..255
    int b = bs >> 3, s = bs & 7;
    int tid = threadIdx.x;
    if (tid == 0) cnt = 0;
    __syncthreads();
    int r0 = s * ROWS_PER_SUB;
    for (int c0 = 0; c0 < ROWS_PER_SUB; c0 += 512) {
        int nrows = ROWS_PER_SUB - c0; if (nrows > 512) nrows = 512;
        int nfl = nrows * ROWF;
        size_t gbase = ((size_t)b * NPRED + r0 + c0) * ROWF;
        for (int idx = tid; idx < nfl; idx += 512) stage[idx] = pred[gbase + idx];
        __syncthreads();
        if (tid < nrows) {
            float obj = stage[tid * ROWF + 4];
            float cls = stage[tid * ROWF + 5];
            float conf = obj * cls;
            if (obj > CONF_T && conf > CONF_T) {
                int r = r0 + c0 + tid;
                u32 slot = atomicAdd(&cnt, 1u);
                if (slot < SUBCAP) {
                    u64 key = ((u64)__float_as_uint(conf) << 32) | (u64)(u32)(~(u32)r);
                    buf[slot] = key;
                }
            }
        }
        __syncthreads();
    }
    u32 c = cnt < SUBCAP ? cnt : SUBCAP;
    if (tid == 0) counts[bs] = c;
    for (u32 t = tid; t < c; t += 512) cand[(size_t)bs * SUBCAP + t] = buf[t];
}

// K2: per-image: gather candidates -> bitonic sort -> top-1000 gather ->
// suppression bit-matrix (column-major, broadcast-j) -> single-wave greedy scan.
__global__ __launch_bounds__(1024) void nms_kernel(const float* __restrict__ pred,
                                                   const u32* __restrict__ counts,
                                                   const u64* __restrict__ candg,
                                                   float* __restrict__ out,      // [B,1000,9]
                                                   float* __restrict__ keepout)  // [B,1000]
{
    __shared__ u64 supc[KW * SUPSTRIDE]; // 128128 B; first CAP entries alias sort buffer
    __shared__ float4 boxes_s[TOPK];     // 16000 B
    __shared__ float  area_s[TOPK];      // 4000 B
    __shared__ float  scores_s[TOPK];    // 4000 B
    __shared__ u64 kw[KW];               // 128 B

    u64* cand = supc;                    // alias: sort buffer lives where supc will go
    int b = blockIdx.x;
    int tid = threadIdx.x;

    if (tid < KW) kw[tid] = 0;
    for (int t = tid; t < CAP; t += 1024) cand[t] = 0;
    __syncthreads();

    // gather sub-buffers (order across subs arbitrary; sort fixes it)
    u32 off = 0;
    for (int s = 0; s < SUBS; ++s) {
        u32 c = counts[b * SUBS + s];
        if (c > SUBCAP) c = SUBCAP;
        u32 lim = (off + c > CAP) ? (CAP - off) : c;
        for (u32 t = tid; t < lim; t += 1024)
            cand[off + t] = candg[(size_t)(b * SUBS + s) * SUBCAP + t];
        off += lim;
    }
    __syncthreads();

    // bitonic sort, descending, CAP elements (zeros pad to the end)
    for (int k = 2; k <= CAP; k <<= 1) {
        for (int j = k >> 1; j > 0; j >>= 1) {
            for (int t = tid; t < CAP; t += 1024) {
                int p = t ^ j;
                if (p > t) {
                    u64 a = cand[t], c2 = cand[p];
                    bool desc = ((t & k) == 0);
                    if (desc ? (a < c2) : (a > c2)) { cand[t] = c2; cand[p] = a; }
                }
            }
            __syncthreads();
        }
    }

    // phase C: top-1000 unpack + gather pred rows + compute boxes
    float sc = 0.f, a6 = 0.f, a7 = 0.f, a8 = 0.f;
    float4 box = make_float4(0.f, 0.f, 0.f, 0.f);
    if (tid < TOPK) {
        u64 key = cand[tid];
        if (key != 0) {
            sc = __uint_as_float((u32)(key >> 32));
            u32 r = ~(u32)key;
            const float* p = pred + ((size_t)b * NPRED + r) * ROWF;
            float x = p[0], y = p[1], w = p[2], h = p[3];
            box = make_float4(x - w * 0.5f, y - h * 0.5f, x + w * 0.5f, y + h * 0.5f);
            a6 = p[6]; a7 = p[7]; a8 = p[8];
            atomicOr(&kw[tid >> 6], 1ull << (tid & 63));
        }
        boxes_s[tid] = box;
        area_s[tid] = (box.z - box.x) * (box.w - box.y);
        scores_s[tid] = sc;
    }
    __syncthreads();   // cand reads done + boxes visible before supc overwrite

    // phase D: suppression matrix, column-major supc[wd*SUPSTRIDE + i].
    // Wave handles a contiguous 64-row i-block; j is wave-uniform -> LDS
    // broadcast reads (conflict-free). Word accumulates in a register and is
    // written once (lane-consecutive writes, conflict-free). Magic-square
    // block assignment balances triangular trip counts across SIMDs whether
    // waves map to SIMDs round-robin or in quarters.
    {
        static const int magic[16] = {0,14,13,3, 11,5,6,8, 7,9,10,4, 12,2,1,15};
        int w = tid >> 6, lane = tid & 63;
        int bw = magic[w];
        int i = bw * 64 + lane;
        bool act = i < TOPK;
        float4 bi = make_float4(0.f, 0.f, 0.f, 0.f);
        float ai = 0.f;
        if (act) { bi = boxes_s[i]; ai = area_s[i]; }
        for (int wd = 0; wd < bw; ++wd)
            if (act) supc[wd * SUPSTRIDE + i] = 0;
        u64 m = 0;
        int curw = bw;
        for (int j = bw * 64 + 1; j < TOPK; ++j) {
            int jw = j >> 6;
            if (jw != curw) {               // wave-uniform branch
                if (act) supc[curw * SUPSTRIDE + i] = m;
                m = 0; curw = jw;
            }
            float4 bj = boxes_s[j];         // broadcast
            float aj = area_s[j];           // broadcast
            float lx = fmaxf(bi.x, bj.x);
            float ly = fmaxf(bi.y, bj.y);
            float rx = fminf(bi.z, bj.z);
            float ry = fminf(bi.w, bj.w);
            float iw = rx - lx; iw = iw > 0.f ? iw : 0.f;
            float ih = ry - ly; ih = ih > 0.f ? ih : 0.f;
            float inter = iw * ih;
            float den = ai + aj - inter + 1e-7f;  // ((ai+aj)-inter)+eps, ref order
            float iou = inter / den;
            if (act && j > i && iou > IOU_T) m |= 1ull << (j & 63);
        }
        if (act) supc[curw * SUPSTRIDE + i] = m;
    }
    __syncthreads();

    // phase E: greedy scan, wave 0 only; skip-ahead over surviving bits.
    if (tid < 64) {
        u64 keepw = (tid < KW) ? kw[tid] : 0ull;
        int i = -1;
        while (true) {
            u64 cb = keepw;
            if (i >= 0) {
                int iw_ = i >> 6;
                int ib = i & 63;
                if (tid < iw_) cb = 0;
                else if (tid == iw_) cb &= (ib == 63) ? 0ull : (~0ull << (ib + 1));
            }
            u64 bal = __ballot(cb != 0);
            if (bal == 0) break;
            int f = __ffsll(bal) - 1;
            u64 wsel = __shfl(cb, f);
            int bb = __ffsll(wsel) - 1;
            i = f * 64 + bb;            // next still-kept box; it is a final survivor
            if (tid < KW) keepw &= ~supc[tid * SUPSTRIDE + i];
        }
        if (tid < KW) kw[tid] = keepw;
    }
    __syncthreads();

    // phase F: write output rows + keep mask
    if (tid < TOPK) {
        bool kp = (kw[tid >> 6] >> (tid & 63)) & 1ull;
        size_t ob = ((size_t)b * TOPK + tid) * ROWF;
        float4 bx = boxes_s[tid];
        out[ob + 0] = kp ? bx.x : 0.f;
        out[ob + 1] = kp ? bx.y : 0.f;
        out[ob + 2] = kp ? bx.z : 0.f;
        out[ob + 3] = kp ? bx.w : 0.f;
        out[ob + 4] = kp ? scores_s[tid] : 0.f;
        out[ob + 5] = 0.f;
        out[ob + 6] = kp ? a6 : 0.f;
        out[ob + 7] = kp ? a7 : 0.f;
        out[ob + 8] = kp ? a8 : 0.f;
        keepout[(size_t)b * TOPK + tid] = kp ? 1.0f : 0.0f;
    }
}

extern "C" void kernel_launch(void* const* d_in, const int* in_sizes, int n_in,
                              void* d_out, int out_size, void* d_ws, size_t ws_size,
                              hipStream_t stream) {
    const float* pred = (const float*)d_in[0];
    float* out = (float*)d_out;                         // [32,1000,9]
    float* keepout = out + (size_t)BATCH * TOPK * ROWF; // [32,1000]
    u32* counts = (u32*)d_ws;                           // 256 u32
    u64* cand = (u64*)((char*)d_ws + 2048);             // 256*1024 u64 = 2 MB

    compact_kernel<<<BATCH * SUBS, 512, 0, stream>>>(pred, counts, cand);
    nms_kernel<<<BATCH, 1024, 0, stream>>>(pred, counts, cand, out, keepout);
}

// Round 4
// 338.717 us; speedup vs baseline: 1.8927x; 1.4612x over previous
//
#include <hip/hip_runtime.h>
#include <stdint.h>

// Match reference numerics: no FMA contraction anywhere (discrete IoU>thres
// decisions flip on 1-ulp differences).
#pragma clang fp contract(off)

#define BATCH 32
#define NPRED 25200
#define ROWF 9
#define TOPK 1000
#define SUBS 16
#define ROWS_PER_SUB (NPRED / SUBS)   // 1575
#define SUBCAP 512
#define CONF_T 0.7f
#define IOU_T 0.45f
#define KW 16          // 1000 bits -> 16 u64 words
#define SUPROW 1024    // global sup stride per word-column
#define LSTRIDE 1001   // LDS sup stride: 16 lanes -> 16 distinct banks

typedef unsigned long long u64;
typedef unsigned int u32;

// ---- workspace layout (bytes) ----
// cand_ws: 512 lists x 512 u64          = 2,097,152
// sup_g  : 32 x 16 x 1024 u64           = 4,194,304   (upper-triangle tiles only)
// bx_ws  : 32 x 1000 float4             =   512,000
// area_ws: 32 x 1000 float              =   128,000
// sa_ws  : 32 x 1000 float4 (sc,a6..8)  =   512,000
// kw_ws  : 32 x 16 u64                  =     4,096
#define WS_CAND 0
#define WS_SUP  (2097152)
#define WS_BX   (WS_SUP + 4194304)
#define WS_AREA (WS_BX + 512000)
#define WS_SA   (WS_AREA + 128000)
#define WS_KW   (WS_SA + 512000)

// K1: compact valid rows of one (image, sub-range) into keys, then bitonic-sort
// the 512-entry sub-list in-block (descending; zeros pad to the end).
// key = (float_bits(conf)<<32) | ~row  -> desc order == (score desc, idx asc),
// exactly jax.lax.top_k tie-breaking.
__global__ __launch_bounds__(512) void compact_sort_kernel(const float* __restrict__ pred,
                                                           u64* __restrict__ cand_ws) {
    __shared__ float stage[512 * ROWF];   // 18432 B
    __shared__ u64 skey[SUBCAP];          // 4096 B
    __shared__ u32 cnt;
    int bs = blockIdx.x;          // 0..511
    int b = bs >> 4, s = bs & 15;
    int tid = threadIdx.x;
    if (tid == 0) cnt = 0;
    skey[tid] = 0;
    __syncthreads();
    int r0 = s * ROWS_PER_SUB;
    for (int c0 = 0; c0 < ROWS_PER_SUB; c0 += 512) {
        int nrows = ROWS_PER_SUB - c0; if (nrows > 512) nrows = 512;
        int nfl = nrows * ROWF;
        size_t g0 = ((size_t)b * NPRED + r0 + c0) * ROWF;  // global float index
        // cooperative copy pred[g0 .. g0+nfl) -> stage[0..nfl), float4 body + peel
        int h = (int)((4 - (g0 & 3)) & 3); if (h > nfl) h = nfl;
        if (tid < h) stage[tid] = pred[g0 + tid];
        int nv = (nfl - h) >> 2;
        const float4* pv = (const float4*)(pred + g0 + h);
        for (int v = tid; v < nv; v += 512) {
            float4 q = pv[v];
            int d = h + v * 4;
            stage[d] = q.x; stage[d + 1] = q.y; stage[d + 2] = q.z; stage[d + 3] = q.w;
        }
        for (int t2 = h + nv * 4 + tid; t2 < nfl; t2 += 512) stage[t2] = pred[g0 + t2];
        __syncthreads();
        if (tid < nrows) {
            float obj = stage[tid * ROWF + 4];
            float cls = stage[tid * ROWF + 5];
            float conf = obj * cls;
            if (obj > CONF_T && conf > CONF_T) {
                int r = r0 + c0 + tid;
                u32 slot = atomicAdd(&cnt, 1u);
                if (slot < SUBCAP)
                    skey[slot] = ((u64)__float_as_uint(conf) << 32) | (u64)(u32)(~(u32)r);
            }
        }
        __syncthreads();
    }
    // bitonic sort, descending, 512 elements, 512 threads (45 passes)
    for (int k = 2; k <= SUBCAP; k <<= 1) {
        for (int j = k >> 1; j > 0; j >>= 1) {
            int t = tid, p = t ^ j;
            if (p > t) {
                u64 a = skey[t], c2 = skey[p];
                bool desc = ((t & k) == 0);
                if (desc ? (a < c2) : (a > c2)) { skey[t] = c2; skey[p] = a; }
            }
            __syncthreads();
        }
    }
    cand_ws[(size_t)bs * SUBCAP + tid] = skey[tid];
}

// K2a: per image, merge 16 sorted sub-lists by exact rank (binary searches),
// take top-1000, gather rows, compute boxes/areas, write SoA + keep0 mask.
__global__ __launch_bounds__(1024) void topk_kernel(const float* __restrict__ pred,
                                                    const u64* __restrict__ cand_ws,
                                                    float4* __restrict__ bx_ws,
                                                    float* __restrict__ area_ws,
                                                    float4* __restrict__ sa_ws,
                                                    u64* __restrict__ kw_ws) {
    __shared__ u64 lists[SUBS * SUBCAP];   // 64 KB
    __shared__ u64 tkey[TOPK];             // 8 KB
    __shared__ u64 kws[KW];
    int b = blockIdx.x, tid = threadIdx.x;
    for (int t = tid; t < SUBS * SUBCAP; t += 1024)
        lists[t] = cand_ws[(size_t)b * SUBS * SUBCAP + t];
    if (tid < KW) kws[tid] = 0;
    if (tid < TOPK) tkey[tid] = 0;
    __syncthreads();
    // rank = own index (elements > key in own sorted list) + sum of
    // count_greater(key) over the other 15 lists. Keys are unique (row id
    // embedded), so ranks are unique and exact.
    for (int g = tid; g < SUBS * SUBCAP; g += 1024) {
        u64 key = lists[g];
        if (!key) continue;
        int li = g >> 9;
        int rank = g & 511;
        for (int l = 0; l < SUBS; ++l) {
            if (l == li) continue;
            const u64* L = lists + (l << 9);
            int lo = 0, hi = SUBCAP;
            while (lo < hi) { int mid = (lo + hi) >> 1; if (L[mid] > key) lo = mid + 1; else hi = mid; }
            rank += lo;
        }
        if (rank < TOPK) tkey[rank] = key;
    }
    __syncthreads();
    if (tid < TOPK) {
        u64 key = tkey[tid];
        float4 box = make_float4(0.f, 0.f, 0.f, 0.f);
        float ar = 0.f;
        float4 sa = make_float4(0.f, 0.f, 0.f, 0.f);
        if (key) {
            float sc = __uint_as_float((u32)(key >> 32));
            u32 r = ~(u32)key;
            const float* p = pred + ((size_t)b * NPRED + r) * ROWF;
            float x = p[0], y = p[1], w = p[2], hh = p[3];
            box = make_float4(x - w * 0.5f, y - hh * 0.5f, x + w * 0.5f, y + hh * 0.5f);
            ar = (box.z - box.x) * (box.w - box.y);
            sa = make_float4(sc, p[6], p[7], p[8]);
            atomicOr(&kws[tid >> 6], 1ull << (tid & 63));
        }
        bx_ws[b * TOPK + tid] = box;
        area_ws[b * TOPK + tid] = ar;
        sa_ws[b * TOPK + tid] = sa;
    }
    __syncthreads();
    if (tid < KW) kw_ws[b * KW + tid] = kws[tid];
}

// K2b: suppression matrix as 136 upper-triangle 64x64 tiles per image,
// one tile per wave (8 blocks/image x 16 waves; wave 15 of each block takes
// one extra tile). j is wave-uniform -> LDS broadcast reads; the 64-bit word
// accumulates in a register; writes are lane-consecutive (coalesced).
__global__ __launch_bounds__(1024) void supmat_kernel(const float4* __restrict__ bx_ws,
                                                      const float* __restrict__ area_ws,
                                                      u64* __restrict__ sup_g) {
    __shared__ float4 bx_s[TOPK];   // 16 KB
    __shared__ float  ar_s[TOPK];   // 4 KB
    int b = blockIdx.x >> 3, q = blockIdx.x & 7;
    int tid = threadIdx.x;
    if (tid < TOPK) { bx_s[tid] = bx_ws[b * TOPK + tid]; ar_s[tid] = area_ws[b * TOPK + tid]; }
    __syncthreads();
    int wave = tid >> 6, lane = tid & 63;
    for (int pass = 0; pass < 2; ++pass) {
        int t = (pass == 0) ? (q * 16 + wave) : ((wave == 15) ? 128 + q : 136);
        if (t >= 136) continue;
        // decode tile t -> (iw, jw), jw >= iw
        int iw = 0, rem = t, c = 16;
        while (rem >= c) { rem -= c; c--; iw++; }
        int jw = iw + rem;
        int i = iw * 64 + lane;
        bool act = i < TOPK;
        float4 bi = act ? bx_s[i] : make_float4(0.f, 0.f, 0.f, 0.f);
        float ai = act ? ar_s[i] : 0.f;
        u64 m = 0;
        int jbase = jw << 6;
        int jend = jbase + 64; if (jend > TOPK) jend = TOPK;
        for (int j = jbase; j < jend; ++j) {
            float4 bj = bx_s[j];            // broadcast
            float aj = ar_s[j];             // broadcast
            float lx = fmaxf(bi.x, bj.x);
            float ly = fmaxf(bi.y, bj.y);
            float rx = fminf(bi.z, bj.z);
            float ry = fminf(bi.w, bj.w);
            float iw2 = rx - lx; iw2 = iw2 > 0.f ? iw2 : 0.f;
            float ih = ry - ly; ih = ih > 0.f ? ih : 0.f;
            float inter = iw2 * ih;
            float den = ai + aj - inter + 1e-7f;  // ((ai+aj)-inter)+eps, ref order
            float iou = inter / den;
            if (act && j > i && iou > IOU_T) m |= 1ull << (j - jbase);
        }
        if (act) sup_g[((size_t)b * KW + jw) * SUPROW + i] = m;
    }
}

// K2c: load sup matrix into LDS (conflict-free stride), single-wave greedy
// skip-ahead scan, write output rows + keep mask.
__global__ __launch_bounds__(1024) void scan_out_kernel(const u64* __restrict__ sup_g,
                                                        const u64* __restrict__ kw_ws,
                                                        const float4* __restrict__ bx_ws,
                                                        const float4* __restrict__ sa_ws,
                                                        float* __restrict__ out,
                                                        float* __restrict__ keepout) {
    __shared__ u64 supc[KW * LSTRIDE];   // 128128 B
    __shared__ u64 kws[KW];
    int b = blockIdx.x, tid = threadIdx.x;
    if (tid < KW) kws[tid] = kw_ws[b * KW + tid];
    const u64* src = sup_g + (size_t)b * KW * SUPROW;
    for (int g2 = tid; g2 < KW * SUPROW / 2; g2 += 1024) {
        int g = g2 * 2;                 // 16B-aligned pair, coalesced
        u64 v0 = src[g], v1 = src[g + 1];
        int jw = g >> 10, ii = g & 1023;
        if (ii < TOPK) supc[jw * LSTRIDE + ii] = v0;
        if (ii + 1 < TOPK) supc[jw * LSTRIDE + ii + 1] = v1;
    }
    __syncthreads();
    if (tid < 64) {
        u64 keepw = (tid < KW) ? kws[tid] : 0ull;
        int i = -1;
        while (true) {
            u64 cb = keepw;
            if (i >= 0) {
                int iw_ = i >> 6, ib = i & 63;
                if (tid < iw_) cb = 0;
                else if (tid == iw_) cb &= (ib == 63) ? 0ull : (~0ull << (ib + 1));
            }
            u64 bal = __ballot(cb != 0);
            if (bal == 0) break;
            int f = __ffsll((long long)bal) - 1;
            u64 wsel = __shfl(cb, f);
            int bb = __ffsll((long long)wsel) - 1;
            i = f * 64 + bb;            // next still-kept box; it is a final survivor
            // only word-columns jw >= i>>6 can have bits from i (j > i);
            // lower words were never written (uninitialized ws) and must be skipped.
            if (tid < KW && tid >= (i >> 6)) keepw &= ~supc[tid * LSTRIDE + i];
        }
        if (tid < KW) kws[tid] = keepw;
    }
    __syncthreads();
    if (tid < TOPK) {
        bool kp = (kws[tid >> 6] >> (tid & 63)) & 1ull;
        float4 bx = bx_ws[b * TOPK + tid];
        float4 sa = sa_ws[b * TOPK + tid];
        size_t ob = ((size_t)b * TOPK + tid) * ROWF;
        out[ob + 0] = kp ? bx.x : 0.f;
        out[ob + 1] = kp ? bx.y : 0.f;
        out[ob + 2] = kp ? bx.z : 0.f;
        out[ob + 3] = kp ? bx.w : 0.f;
        out[ob + 4] = kp ? sa.x : 0.f;
        out[ob + 5] = 0.f;
        out[ob + 6] = kp ? sa.y : 0.f;
        out[ob + 7] = kp ? sa.z : 0.f;
        out[ob + 8] = kp ? sa.w : 0.f;
        keepout[(size_t)b * TOPK + tid] = kp ? 1.0f : 0.0f;
    }
}

extern "C" void kernel_launch(void* const* d_in, const int* in_sizes, int n_in,
                              void* d_out, int out_size, void* d_ws, size_t ws_size,
                              hipStream_t stream) {
    const float* pred = (const float*)d_in[0];
    float* out = (float*)d_out;                         // [32,1000,9]
    float* keepout = out + (size_t)BATCH * TOPK * ROWF; // [32,1000]
    char* ws = (char*)d_ws;
    u64* cand_ws = (u64*)(ws + WS_CAND);
    u64* sup_g = (u64*)(ws + WS_SUP);
    float4* bx_ws = (float4*)(ws + WS_BX);
    float* area_ws = (float*)(ws + WS_AREA);
    float4* sa_ws = (float4*)(ws + WS_SA);
    u64* kw_ws = (u64*)(ws + WS_KW);

    compact_sort_kernel<<<BATCH * SUBS, 512, 0, stream>>>(pred, cand_ws);
    topk_kernel<<<BATCH, 1024, 0, stream>>>(pred, cand_ws, bx_ws, area_ws, sa_ws, kw_ws);
    supmat_kernel<<<BATCH * 8, 1024, 0, stream>>>(bx_ws, area_ws, sup_g);
    scan_out_kernel<<<BATCH, 1024, 0, stream>>>(sup_g, kw_ws, bx_ws, sa_ws, out, keepout);
}

// Round 5
// 200.324 us; speedup vs baseline: 3.2003x; 1.6908x over previous
//
#include <hip/hip_runtime.h>
#include <stdint.h>

// Match reference numerics: no FMA contraction anywhere (discrete IoU>thres
// decisions flip on 1-ulp differences).
#pragma clang fp contract(off)

#define BATCH 32
#define NPRED 25200
#define ROWF 9
#define TOPK 1000
#define SUBS 8
#define ROWS_PER_SUB (NPRED / SUBS)   // 3150
#define SUBCAP 512
#define CONF_T 0.7f
#define IOU_T 0.45f
#define KW 16          // 1000 bits -> 16 u64 words
#define SUPROW 1024    // global sup stride per word-column

typedef unsigned long long u64;
typedef unsigned int u32;

// ---- workspace layout (bytes) ----
#define WS_CAND 0                      // 256 lists x 512 u64 = 1,048,576
#define WS_SUP  (1048576)              // 32 x 16 x 1024 u64  = 4,194,304
#define WS_BX   (WS_SUP + 4194304)     // 32 x 1000 float4    =   512,000
#define WS_AREA (WS_BX + 512000)       // 32 x 1000 float     =   128,000
#define WS_SA   (WS_AREA + 128000)     // 32 x 1000 float4    =   512,000
#define WS_KW   (WS_SA + 512000)       // 32 x 16 u64         =     4,096

// K1: compact valid rows of one (image, sub-range) into keys, then bitonic-sort
// the 512-entry sub-list in-block (descending; zeros pad to the end).
// key = (float_bits(conf)<<32) | ~row  -> desc order == (score desc, idx asc),
// exactly jax.lax.top_k tie-breaking. Expected ~317 valid rows per 3150.
__global__ __launch_bounds__(512) void compact_sort_kernel(const float* __restrict__ pred,
                                                           u64* __restrict__ cand_ws) {
    __shared__ float stage[512 * ROWF];   // 18432 B
    __shared__ u64 skey[SUBCAP];          // 4096 B
    __shared__ u32 cnt;
    int bs = blockIdx.x;          // 0..255
    int b = bs >> 3, s = bs & 7;
    int tid = threadIdx.x;
    if (tid == 0) cnt = 0;
    skey[tid] = 0;
    __syncthreads();
    int r0 = s * ROWS_PER_SUB;
    for (int c0 = 0; c0 < ROWS_PER_SUB; c0 += 512) {
        int nrows = ROWS_PER_SUB - c0; if (nrows > 512) nrows = 512;
        int nfl = nrows * ROWF;
        size_t g0 = ((size_t)b * NPRED + r0 + c0) * ROWF;  // global float index
        // cooperative copy pred[g0 .. g0+nfl) -> stage[0..nfl), float4 body + peel
        int h = (int)((4 - (g0 & 3)) & 3); if (h > nfl) h = nfl;
        if (tid < h) stage[tid] = pred[g0 + tid];
        int nv = (nfl - h) >> 2;
        const float4* pv = (const float4*)(pred + g0 + h);
        for (int v = tid; v < nv; v += 512) {
            float4 q = pv[v];
            int d = h + v * 4;
            stage[d] = q.x; stage[d + 1] = q.y; stage[d + 2] = q.z; stage[d + 3] = q.w;
        }
        for (int t2 = h + nv * 4 + tid; t2 < nfl; t2 += 512) stage[t2] = pred[g0 + t2];
        __syncthreads();
        if (tid < nrows) {
            float obj = stage[tid * ROWF + 4];
            float cls = stage[tid * ROWF + 5];
            float conf = obj * cls;
            if (obj > CONF_T && conf > CONF_T) {
                int r = r0 + c0 + tid;
                u32 slot = atomicAdd(&cnt, 1u);
                if (slot < SUBCAP)
                    skey[slot] = ((u64)__float_as_uint(conf) << 32) | (u64)(u32)(~(u32)r);
            }
        }
        __syncthreads();
    }
    // bitonic sort, descending, 512 elements, 512 threads (45 passes)
    for (int k = 2; k <= SUBCAP; k <<= 1) {
        for (int j = k >> 1; j > 0; j >>= 1) {
            int t = tid, p = t ^ j;
            if (p > t) {
                u64 a = skey[t], c2 = skey[p];
                bool desc = ((t & k) == 0);
                if (desc ? (a < c2) : (a > c2)) { skey[t] = c2; skey[p] = a; }
            }
            __syncthreads();
        }
    }
    cand_ws[(size_t)bs * SUBCAP + tid] = skey[tid];
}

// K2a: per image, merge 8 sorted sub-lists by exact rank. Rank of a key =
// sum over ALL 8 lists of count(elements > key) (own list contributes the
// key's own index; keys unique). Searches run as a breadth-interleaved
// power-of-2 ladder: per round, 8 independent LDS probes (one waitcnt),
// fully unrolled -> latency-tolerant.
__global__ __launch_bounds__(1024) void topk_kernel(const float* __restrict__ pred,
                                                    const u64* __restrict__ cand_ws,
                                                    float4* __restrict__ bx_ws,
                                                    float* __restrict__ area_ws,
                                                    float4* __restrict__ sa_ws,
                                                    u64* __restrict__ kw_ws) {
    __shared__ u64 lists[SUBS * SUBCAP];   // 32 KB
    __shared__ u64 tkey[TOPK];             // 8 KB
    __shared__ u64 kws[KW];
    int b = blockIdx.x, tid = threadIdx.x;
    for (int t = tid; t < SUBS * SUBCAP; t += 1024)
        lists[t] = cand_ws[(size_t)b * SUBS * SUBCAP + t];
    if (tid < KW) kws[tid] = 0;
    if (tid < TOPK) tkey[tid] = 0;
    __syncthreads();
    for (int k = 0; k < (SUBS * SUBCAP) / 1024; ++k) {
        int g = tid + (k << 10);
        u64 key = lists[g];
        if (!key) continue;
        int lo[SUBS];
#pragma unroll
        for (int l = 0; l < SUBS; ++l) lo[l] = 0;
#pragma unroll
        for (int w2 = SUBCAP; w2 >= 1; w2 >>= 1) {   // 10 rounds
#pragma unroll
            for (int l = 0; l < SUBS; ++l) {
                int p = lo[l] + w2;
                if (p <= SUBCAP && lists[(l << 9) + p - 1] > key) lo[l] = p;
            }
        }
        int rank = 0;
#pragma unroll
        for (int l = 0; l < SUBS; ++l) rank += lo[l];
        if (rank < TOPK) tkey[rank] = key;
    }
    __syncthreads();
    if (tid < TOPK) {
        u64 key = tkey[tid];
        float4 box = make_float4(0.f, 0.f, 0.f, 0.f);
        float ar = 0.f;
        float4 sa = make_float4(0.f, 0.f, 0.f, 0.f);
        if (key) {
            float sc = __uint_as_float((u32)(key >> 32));
            u32 r = ~(u32)key;
            const float* p = pred + ((size_t)b * NPRED + r) * ROWF;
            float x = p[0], y = p[1], w = p[2], hh = p[3];
            box = make_float4(x - w * 0.5f, y - hh * 0.5f, x + w * 0.5f, y + hh * 0.5f);
            ar = (box.z - box.x) * (box.w - box.y);
            sa = make_float4(sc, p[6], p[7], p[8]);
            atomicOr(&kws[tid >> 6], 1ull << (tid & 63));
        }
        bx_ws[b * TOPK + tid] = box;
        area_ws[b * TOPK + tid] = ar;
        sa_ws[b * TOPK + tid] = sa;
    }
    __syncthreads();
    if (tid < KW) kw_ws[b * KW + tid] = kws[tid];
}

// K2b: suppression matrix as 136 upper-triangle 64x64 tiles per image,
// one tile per wave. j is wave-uniform -> LDS broadcast reads; the 64-bit
// word accumulates in a register; writes are lane-consecutive (coalesced).
__global__ __launch_bounds__(1024) void supmat_kernel(const float4* __restrict__ bx_ws,
                                                      const float* __restrict__ area_ws,
                                                      u64* __restrict__ sup_g) {
    __shared__ float4 bx_s[TOPK];   // 16 KB
    __shared__ float  ar_s[TOPK];   // 4 KB
    int b = blockIdx.x >> 3, q = blockIdx.x & 7;
    int tid = threadIdx.x;
    if (tid < TOPK) { bx_s[tid] = bx_ws[b * TOPK + tid]; ar_s[tid] = area_ws[b * TOPK + tid]; }
    __syncthreads();
    int wave = tid >> 6, lane = tid & 63;
    for (int pass = 0; pass < 2; ++pass) {
        int t = (pass == 0) ? (q * 16 + wave) : ((wave == 15) ? 128 + q : 136);
        if (t >= 136) continue;
        // decode tile t -> (iw, jw), jw >= iw
        int iw = 0, rem = t, c = 16;
        while (rem >= c) { rem -= c; c--; iw++; }
        int jw = iw + rem;
        int i = iw * 64 + lane;
        bool act = i < TOPK;
        float4 bi = act ? bx_s[i] : make_float4(0.f, 0.f, 0.f, 0.f);
        float ai = act ? ar_s[i] : 0.f;
        u64 m = 0;
        int jbase = jw << 6;
        int jend = jbase + 64; if (jend > TOPK) jend = TOPK;
        for (int j = jbase; j < jend; ++j) {
            float4 bj = bx_s[j];            // broadcast
            float aj = ar_s[j];             // broadcast
            float lx = fmaxf(bi.x, bj.x);
            float ly = fmaxf(bi.y, bj.y);
            float rx = fminf(bi.z, bj.z);
            float ry = fminf(bi.w, bj.w);
            float iw2 = rx - lx; iw2 = iw2 > 0.f ? iw2 : 0.f;
            float ih = ry - ly; ih = ih > 0.f ? ih : 0.f;
            float inter = iw2 * ih;
            float den = ai + aj - inter + 1e-7f;  // ((ai+aj)-inter)+eps, ref order
            float iou = inter / den;
            if (act && j > i && iou > IOU_T) m |= 1ull << (j - jbase);
        }
        if (act) sup_g[((size_t)b * KW + jw) * SUPROW + i] = m;
    }
}

// K2c: register-resident greedy scan. Thread (wave w, lane l) holds
// sup[b][word w][row bi*64+l] for bi=0..15 in registers (coalesced preload).
// Per 64-row block bi: wave bi runs the serial greedy loop with its diagonal
// words exchanged via __shfl (no LDS in the dependent chain, ~60 cy/survivor);
// then waves w>bi apply the accepted set from registers via a shfl-xor
// OR-butterfly. keep words live in a tiny LDS array between phases.
__global__ __launch_bounds__(1024) void scan_out_kernel(const u64* __restrict__ sup_g,
                                                        const u64* __restrict__ kw_ws,
                                                        const float4* __restrict__ bx_ws,
                                                        const float4* __restrict__ sa_ws,
                                                        float* __restrict__ out,
                                                        float* __restrict__ keepout) {
    __shared__ u64 keep_lds[KW];
    __shared__ u64 acc_lds;
    int b = blockIdx.x, tid = threadIdx.x;
    int w = tid >> 6, lane = tid & 63;
    const u64* S = sup_g + (size_t)b * KW * SUPROW;

    u64 sup_reg[KW];
#pragma unroll
    for (int bi = 0; bi < KW; ++bi)
        sup_reg[bi] = S[(size_t)w * SUPROW + (bi << 6) + lane];   // garbage for bi>=w: never used
    u64 diagreg = S[(size_t)w * SUPROW + (w << 6) + lane];        // own diag tile word

    if (tid < KW) keep_lds[tid] = kw_ws[b * KW + tid];
    __syncthreads();

#pragma unroll
    for (int bi = 0; bi < KW; ++bi) {
        if (w == bi) {
            // serial greedy within word bi (wave-uniform loop)
            u64 cur = keep_lds[bi];
            u64 accepted = 0;
            while (cur) {
                int i = __ffsll((long long)cur) - 1;
                accepted |= 1ull << i;
                cur &= cur - 1;                 // clear bit i
                u64 wi = __shfl(diagreg, i);    // row i's within-word suppression (bits > i only)
                cur &= ~wi;
            }
            if (lane == 0) { keep_lds[bi] = accepted; acc_lds = accepted; }
        }
        __syncthreads();
        if (w > bi) {
            u64 A = acc_lds;
            u64 val = ((A >> lane) & 1ull) ? sup_reg[bi] : 0ull;  // static index (unrolled)
#pragma unroll
            for (int d = 1; d < 64; d <<= 1) val |= __shfl_xor(val, d);
            if (lane == 0) keep_lds[w] &= ~val;
        }
        __syncthreads();
    }

    if (tid < TOPK) {
        bool kp = (keep_lds[tid >> 6] >> (tid & 63)) & 1ull;
        float4 bx = bx_ws[b * TOPK + tid];
        float4 sa = sa_ws[b * TOPK + tid];
        size_t ob = ((size_t)b * TOPK + tid) * ROWF;
        out[ob + 0] = kp ? bx.x : 0.f;
        out[ob + 1] = kp ? bx.y : 0.f;
        out[ob + 2] = kp ? bx.z : 0.f;
        out[ob + 3] = kp ? bx.w : 0.f;
        out[ob + 4] = kp ? sa.x : 0.f;
        out[ob + 5] = 0.f;
        out[ob + 6] = kp ? sa.y : 0.f;
        out[ob + 7] = kp ? sa.z : 0.f;
        out[ob + 8] = kp ? sa.w : 0.f;
        keepout[(size_t)b * TOPK + tid] = kp ? 1.0f : 0.0f;
    }
}

extern "C" void kernel_launch(void* const* d_in, const int* in_sizes, int n_in,
                              void* d_out, int out_size, void* d_ws, size_t ws_size,
                              hipStream_t stream) {
    const float* pred = (const float*)d_in[0];
    float* out = (float*)d_out;                         // [32,1000,9]
    float* keepout = out + (size_t)BATCH * TOPK * ROWF; // [32,1000]
    char* ws = (char*)d_ws;
    u64* cand_ws = (u64*)(ws + WS_CAND);
    u64* sup_g = (u64*)(ws + WS_SUP);
    float4* bx_ws = (float4*)(ws + WS_BX);
    float* area_ws = (float*)(ws + WS_AREA);
    float4* sa_ws = (float4*)(ws + WS_SA);
    u64* kw_ws = (u64*)(ws + WS_KW);

    compact_sort_kernel<<<BATCH * SUBS, 512, 0, stream>>>(pred, cand_ws);
    topk_kernel<<<BATCH, 1024, 0, stream>>>(pred, cand_ws, bx_ws, area_ws, sa_ws, kw_ws);
    supmat_kernel<<<BATCH * 8, 1024, 0, stream>>>(bx_ws, area_ws, sup_g);
    scan_out_kernel<<<BATCH, 1024, 0, stream>>>(sup_g, kw_ws, bx_ws, sa_ws, out, keepout);
}

// Round 6
// 142.893 us; speedup vs baseline: 4.4866x; 1.4019x over previous
//
#include <hip/hip_runtime.h>
#include <stdint.h>

// Match reference numerics: no FMA contraction anywhere (discrete IoU>thres
// decisions flip on 1-ulp differences).
#pragma clang fp contract(off)

#define BATCH 32
#define NPRED 25200
#define ROWF 9
#define TOPK 1000
#define SUBS 8
#define ROWS_PER_SUB (NPRED / SUBS)   // 3150
#define SUBCAP 512
#define CONF_T 0.7f
#define IOU_T 0.45f
#define KW 16          // 1000 bits -> 16 u64 words
#define SUPROW 1024    // global sup stride per word-column

typedef unsigned long long u64;
typedef unsigned int u32;

// ---- workspace layout (bytes) ----
#define WS_CAND 0                      // 256 lists x 512 u64 = 1,048,576
#define WS_SUP  (1048576)              // 32 x 16 x 1024 u64  = 4,194,304
#define WS_BX   (WS_SUP + 4194304)     // 32 x 1000 float4    =   512,000
#define WS_AREA (WS_BX + 512000)       // 32 x 1000 float     =   128,000
#define WS_SA   (WS_AREA + 128000)     // 32 x 1000 float4    =   512,000
#define WS_KW   (WS_SA + 512000)       // 32 x 16 u64         =     4,096

__device__ __forceinline__ u64 readlane64(u64 v, int l) {
    // wave-uniform lane index -> v_readlane_b32 x2 (VALU, no LDS pipe)
    u32 lo = __builtin_amdgcn_readlane((u32)v, (u32)l);
    u32 hi = __builtin_amdgcn_readlane((u32)(v >> 32), (u32)l);
    return ((u64)hi << 32) | lo;
}

// K1: compact valid rows of one (image, sub-range) into keys, then bitonic-sort
// the 512-entry sub-list in-block (descending; zeros pad to the end).
// key = (float_bits(conf)<<32) | ~row  -> desc order == (score desc, idx asc),
// exactly jax.lax.top_k tie-breaking. Expected ~317 valid rows per 3150.
__global__ __launch_bounds__(512) void compact_sort_kernel(const float* __restrict__ pred,
                                                           u64* __restrict__ cand_ws) {
    __shared__ float stage[512 * ROWF];   // 18432 B
    __shared__ u64 skey[SUBCAP];          // 4096 B
    __shared__ u32 cnt;
    int bs = blockIdx.x;          // 0..255
    int b = bs >> 3, s = bs & 7;
    int tid = threadIdx.x;
    if (tid == 0) cnt = 0;
    skey[tid] = 0;
    __syncthreads();
    int r0 = s * ROWS_PER_SUB;
    for (int c0 = 0; c0 < ROWS_PER_SUB; c0 += 512) {
        int nrows = ROWS_PER_SUB - c0; if (nrows > 512) nrows = 512;
        int nfl = nrows * ROWF;
        size_t g0 = ((size_t)b * NPRED + r0 + c0) * ROWF;  // global float index
        // cooperative copy pred[g0 .. g0+nfl) -> stage[0..nfl), float4 body + peel
        int h = (int)((4 - (g0 & 3)) & 3); if (h > nfl) h = nfl;
        if (tid < h) stage[tid] = pred[g0 + tid];
        int nv = (nfl - h) >> 2;
        const float4* pv = (const float4*)(pred + g0 + h);
        for (int v = tid; v < nv; v += 512) {
            float4 q = pv[v];
            int d = h + v * 4;
            stage[d] = q.x; stage[d + 1] = q.y; stage[d + 2] = q.z; stage[d + 3] = q.w;
        }
        for (int t2 = h + nv * 4 + tid; t2 < nfl; t2 += 512) stage[t2] = pred[g0 + t2];
        __syncthreads();
        if (tid < nrows) {
            float obj = stage[tid * ROWF + 4];
            float cls = stage[tid * ROWF + 5];
            float conf = obj * cls;
            if (obj > CONF_T && conf > CONF_T) {
                int r = r0 + c0 + tid;
                u32 slot = atomicAdd(&cnt, 1u);
                if (slot < SUBCAP)
                    skey[slot] = ((u64)__float_as_uint(conf) << 32) | (u64)(u32)(~(u32)r);
            }
        }
        __syncthreads();
    }
    // bitonic sort, descending, 512 elements, 512 threads (45 passes)
    for (int k = 2; k <= SUBCAP; k <<= 1) {
        for (int j = k >> 1; j > 0; j >>= 1) {
            int t = tid, p = t ^ j;
            if (p > t) {
                u64 a = skey[t], c2 = skey[p];
                bool desc = ((t & k) == 0);
                if (desc ? (a < c2) : (a > c2)) { skey[t] = c2; skey[p] = a; }
            }
            __syncthreads();
        }
    }
    cand_ws[(size_t)bs * SUBCAP + tid] = skey[tid];
}

// K2a: per image, merge 8 sorted sub-lists by exact rank. Rank of a key =
// sum over ALL 8 lists of count(elements > key) (own list contributes the
// key's own index; keys unique). Searches run as a breadth-interleaved
// power-of-2 ladder: per round, 8 independent LDS probes (one waitcnt),
// fully unrolled -> latency-tolerant.
__global__ __launch_bounds__(1024) void topk_kernel(const float* __restrict__ pred,
                                                    const u64* __restrict__ cand_ws,
                                                    float4* __restrict__ bx_ws,
                                                    float* __restrict__ area_ws,
                                                    float4* __restrict__ sa_ws,
                                                    u64* __restrict__ kw_ws) {
    __shared__ u64 lists[SUBS * SUBCAP];   // 32 KB
    __shared__ u64 tkey[TOPK];             // 8 KB
    __shared__ u64 kws[KW];
    int b = blockIdx.x, tid = threadIdx.x;
    for (int t = tid; t < SUBS * SUBCAP; t += 1024)
        lists[t] = cand_ws[(size_t)b * SUBS * SUBCAP + t];
    if (tid < KW) kws[tid] = 0;
    if (tid < TOPK) tkey[tid] = 0;
    __syncthreads();
    for (int k = 0; k < (SUBS * SUBCAP) / 1024; ++k) {
        int g = tid + (k << 10);
        u64 key = lists[g];
        if (!key) continue;
        int lo[SUBS];
#pragma unroll
        for (int l = 0; l < SUBS; ++l) lo[l] = 0;
#pragma unroll
        for (int w2 = SUBCAP; w2 >= 1; w2 >>= 1) {   // 10 rounds
#pragma unroll
            for (int l = 0; l < SUBS; ++l) {
                int p = lo[l] + w2;
                if (p <= SUBCAP && lists[(l << 9) + p - 1] > key) lo[l] = p;
            }
        }
        int rank = 0;
#pragma unroll
        for (int l = 0; l < SUBS; ++l) rank += lo[l];
        if (rank < TOPK) tkey[rank] = key;
    }
    __syncthreads();
    if (tid < TOPK) {
        u64 key = tkey[tid];
        float4 box = make_float4(0.f, 0.f, 0.f, 0.f);
        float ar = 0.f;
        float4 sa = make_float4(0.f, 0.f, 0.f, 0.f);
        if (key) {
            float sc = __uint_as_float((u32)(key >> 32));
            u32 r = ~(u32)key;
            const float* p = pred + ((size_t)b * NPRED + r) * ROWF;
            float x = p[0], y = p[1], w = p[2], hh = p[3];
            box = make_float4(x - w * 0.5f, y - hh * 0.5f, x + w * 0.5f, y + hh * 0.5f);
            ar = (box.z - box.x) * (box.w - box.y);
            sa = make_float4(sc, p[6], p[7], p[8]);
            atomicOr(&kws[tid >> 6], 1ull << (tid & 63));
        }
        bx_ws[b * TOPK + tid] = box;
        area_ws[b * TOPK + tid] = ar;
        sa_ws[b * TOPK + tid] = sa;
    }
    __syncthreads();
    if (tid < KW) kw_ws[b * KW + tid] = kws[tid];
}

// K2b: suppression matrix as 136 upper-triangle 64x64 tiles per image,
// one tile per wave. j is wave-uniform -> LDS broadcast reads; the 64-bit
// word accumulates in a register; writes are lane-consecutive (coalesced).
__global__ __launch_bounds__(1024) void supmat_kernel(const float4* __restrict__ bx_ws,
                                                      const float* __restrict__ area_ws,
                                                      u64* __restrict__ sup_g) {
    __shared__ float4 bx_s[TOPK];   // 16 KB
    __shared__ float  ar_s[TOPK];   // 4 KB
    int b = blockIdx.x >> 3, q = blockIdx.x & 7;
    int tid = threadIdx.x;
    if (tid < TOPK) { bx_s[tid] = bx_ws[b * TOPK + tid]; ar_s[tid] = area_ws[b * TOPK + tid]; }
    __syncthreads();
    int wave = tid >> 6, lane = tid & 63;
    for (int pass = 0; pass < 2; ++pass) {
        int t = (pass == 0) ? (q * 16 + wave) : ((wave == 15) ? 128 + q : 136);
        if (t >= 136) continue;
        // decode tile t -> (iw, jw), jw >= iw
        int iw = 0, rem = t, c = 16;
        while (rem >= c) { rem -= c; c--; iw++; }
        int jw = iw + rem;
        int i = iw * 64 + lane;
        bool act = i < TOPK;
        float4 bi = act ? bx_s[i] : make_float4(0.f, 0.f, 0.f, 0.f);
        float ai = act ? ar_s[i] : 0.f;
        u64 m = 0;
        int jbase = jw << 6;
        int jend = jbase + 64; if (jend > TOPK) jend = TOPK;
        for (int j = jbase; j < jend; ++j) {
            float4 bj = bx_s[j];            // broadcast
            float aj = ar_s[j];             // broadcast
            float lx = fmaxf(bi.x, bj.x);
            float ly = fmaxf(bi.y, bj.y);
            float rx = fminf(bi.z, bj.z);
            float ry = fminf(bi.w, bj.w);
            float iw2 = rx - lx; iw2 = iw2 > 0.f ? iw2 : 0.f;
            float ih = ry - ly; ih = ih > 0.f ? ih : 0.f;
            float inter = iw2 * ih;
            float den = ai + aj - inter + 1e-7f;  // ((ai+aj)-inter)+eps, ref order
            float iou = inter / den;
            if (act && j > i && iou > IOU_T) m |= 1ull << (j - jbase);
        }
        if (act) sup_g[((size_t)b * KW + jw) * SUPROW + i] = m;
    }
}

// K2c: sparse register-resident greedy scan.
// Thread (wave w, lane l) holds sup word-column w for row bi*64+l per block bi.
// Key insight: a box with an all-zero suppression mask is accepted without
// affecting anything -> the serial loop only visits rows that actually
// suppress (ballot-gated; ~1-5 per word for this data). Uniform-index
// broadcasts use v_readlane (VALU) instead of ds_bpermute (LDS pipe).
__global__ __launch_bounds__(1024) void scan_out_kernel(const u64* __restrict__ sup_g,
                                                        const u64* __restrict__ kw_ws,
                                                        const float4* __restrict__ bx_ws,
                                                        const float4* __restrict__ sa_ws,
                                                        float* __restrict__ out,
                                                        float* __restrict__ keepout) {
    __shared__ u64 keep_lds[KW];
    __shared__ u64 acc_lds;
    int b = blockIdx.x, tid = threadIdx.x;
    int w = tid >> 6, lane = tid & 63;
    const u64* S = sup_g + (size_t)b * KW * SUPROW;

    u64 sup_reg[KW];
    u64 diagreg = 0;
#pragma unroll
    for (int bi = 0; bi < KW; ++bi) {
        sup_reg[bi] = S[(size_t)w * SUPROW + (bi << 6) + lane]; // rows>=TOPK: garbage, gated off
        if (bi == w) diagreg = sup_reg[bi];
    }
    if (tid < KW) keep_lds[tid] = kw_ws[b * KW + tid];
    __syncthreads();

    u64 nzmask = __ballot(diagreg != 0);   // rows of this word with in-word suppression

#pragma unroll
    for (int bi = 0; bi < KW; ++bi) {
        if (w == bi) {
            // serial greedy within word bi; only suppressor rows enter the loop
            u64 cur = keep_lds[bi];
            u64 active = cur & nzmask;
            while (active) {
                int i = __ffsll((long long)active) - 1;
                u64 wi = readlane64(diagreg, i);   // row i's mask (bits > i only)
                active &= active - 1;              // retire bit i
                cur &= ~wi;
                active &= ~wi;                     // suppressed rows can't suppress
            }
            if (lane == 0) { keep_lds[bi] = cur; acc_lds = cur; }
        }
        __syncthreads();
        if (w > bi) {
            u64 A = acc_lds;                       // accepted set of block bi
            u64 myv = sup_reg[bi];                 // row (bi*64+lane)'s mask over word w
            bool accb = (A >> lane) & 1ull;
            u64 lanes = __ballot(accb && myv != 0ull);
            if (lanes) {                           // rare: sparse suppression
                u64 wred = 0;
                while (lanes) {
                    int l = __ffsll((long long)lanes) - 1;
                    wred |= readlane64(myv, l);
                    lanes &= lanes - 1;
                }
                if (lane == 0) keep_lds[w] &= ~wred;
            }
        }
        __syncthreads();
    }

    if (tid < TOPK) {
        bool kp = (keep_lds[tid >> 6] >> (tid & 63)) & 1ull;
        float4 bx = bx_ws[b * TOPK + tid];
        float4 sa = sa_ws[b * TOPK + tid];
        size_t ob = ((size_t)b * TOPK + tid) * ROWF;
        out[ob + 0] = kp ? bx.x : 0.f;
        out[ob + 1] = kp ? bx.y : 0.f;
        out[ob + 2] = kp ? bx.z : 0.f;
        out[ob + 3] = kp ? bx.w : 0.f;
        out[ob + 4] = kp ? sa.x : 0.f;
        out[ob + 5] = 0.f;
        out[ob + 6] = kp ? sa.y : 0.f;
        out[ob + 7] = kp ? sa.z : 0.f;
        out[ob + 8] = kp ? sa.w : 0.f;
        keepout[(size_t)b * TOPK + tid] = kp ? 1.0f : 0.0f;
    }
}

extern "C" void kernel_launch(void* const* d_in, const int* in_sizes, int n_in,
                              void* d_out, int out_size, void* d_ws, size_t ws_size,
                              hipStream_t stream) {
    const float* pred = (const float*)d_in[0];
    float* out = (float*)d_out;                         // [32,1000,9]
    float* keepout = out + (size_t)BATCH * TOPK * ROWF; // [32,1000]
    char* ws = (char*)d_ws;
    u64* cand_ws = (u64*)(ws + WS_CAND);
    u64* sup_g = (u64*)(ws + WS_SUP);
    float4* bx_ws = (float4*)(ws + WS_BX);
    float* area_ws = (float*)(ws + WS_AREA);
    float4* sa_ws = (float4*)(ws + WS_SA);
    u64* kw_ws = (u64*)(ws + WS_KW);

    compact_sort_kernel<<<BATCH * SUBS, 512, 0, stream>>>(pred, cand_ws);
    topk_kernel<<<BATCH, 1024, 0, stream>>>(pred, cand_ws, bx_ws, area_ws, sa_ws, kw_ws);
    supmat_kernel<<<BATCH * 8, 1024, 0, stream>>>(bx_ws, area_ws, sup_g);
    scan_out_kernel<<<BATCH, 1024, 0, stream>>>(sup_g, kw_ws, bx_ws, sa_ws, out, keepout);
}

// Round 7
// 131.683 us; speedup vs baseline: 4.8685x; 1.0851x over previous
//
#include <hip/hip_runtime.h>
#include <stdint.h>

// Match reference numerics: no FMA contraction anywhere (discrete IoU>thres
// decisions flip on 1-ulp differences).
#pragma clang fp contract(off)

#define BATCH 32
#define NPRED 25200
#define ROWF 9
#define TOPK 1000
#define SUBS 8
#define ROWS_PER_SUB (NPRED / SUBS)   // 3150
#define SUBCAP 512
#define CONF_T 0.7f
#define IOU_T 0.45f
#define KW 16          // 1000 bits -> 16 u64 words
#define SUPROW 1024    // global sup stride per word-column
#define TKROW 1024     // tkey stride per image

typedef unsigned long long u64;
typedef unsigned int u32;

// ---- workspace layout (bytes) ----
#define WS_CAND 0                      // 256 lists x 512 u64 = 1,048,576
#define WS_TKEY (1048576)              // 32 x 1024 u64       =   262,144
#define WS_SUP  (WS_TKEY + 262144)     // 32 x 16 x 1024 u64  = 4,194,304

__device__ __forceinline__ u64 readlane64(u64 v, int l) {
    // wave-uniform lane index -> v_readlane_b32 x2 (VALU, no LDS pipe)
    u32 lo = __builtin_amdgcn_readlane((u32)v, (u32)l);
    u32 hi = __builtin_amdgcn_readlane((u32)(v >> 32), (u32)l);
    return ((u64)hi << 32) | lo;
}

// K1: compact valid rows of one (image, sub-range) into keys, then bitonic-sort
// the 512-entry sub-list in-block (descending; zeros pad to the end).
// key = (float_bits(conf)<<32) | ~row  -> desc order == (score desc, idx asc),
// exactly jax.lax.top_k tie-breaking. ~317 valid rows per 3150 expected;
// SUBCAP=512 is mean+11.5 sigma. Also zeroes this block's slice of tkey_ws
// (0xAA-poisoned; rank_kernel only writes slots with rank<TOPK).
__global__ __launch_bounds__(512) void compact_sort_kernel(const float* __restrict__ pred,
                                                           u64* __restrict__ cand_ws,
                                                           u64* __restrict__ tkey_ws) {
    __shared__ float stage[512 * ROWF];   // 18432 B
    __shared__ u64 skey[SUBCAP];          // 4096 B
    __shared__ u32 cnt;
    int bs = blockIdx.x;          // 0..255
    int b = bs >> 3, s = bs & 7;
    int tid = threadIdx.x;
    if (tid == 0) cnt = 0;
    skey[tid] = 0;
    if (tid < 128) tkey_ws[bs * 128 + tid] = 0;   // 256 blocks x 128 = 32 x 1024
    __syncthreads();
    int r0 = s * ROWS_PER_SUB;
    for (int c0 = 0; c0 < ROWS_PER_SUB; c0 += 512) {
        int nrows = ROWS_PER_SUB - c0; if (nrows > 512) nrows = 512;
        int nfl = nrows * ROWF;
        size_t g0 = ((size_t)b * NPRED + r0 + c0) * ROWF;  // global float index
        // cooperative copy pred[g0 .. g0+nfl) -> stage[0..nfl), float4 body + peel
        int h = (int)((4 - (g0 & 3)) & 3); if (h > nfl) h = nfl;
        if (tid < h) stage[tid] = pred[g0 + tid];
        int nv = (nfl - h) >> 2;
        const float4* pv = (const float4*)(pred + g0 + h);
        for (int v = tid; v < nv; v += 512) {
            float4 q = pv[v];
            int d = h + v * 4;
            stage[d] = q.x; stage[d + 1] = q.y; stage[d + 2] = q.z; stage[d + 3] = q.w;
        }
        for (int t2 = h + nv * 4 + tid; t2 < nfl; t2 += 512) stage[t2] = pred[g0 + t2];
        __syncthreads();
        if (tid < nrows) {
            float obj = stage[tid * ROWF + 4];
            float cls = stage[tid * ROWF + 5];
            float conf = obj * cls;
            if (obj > CONF_T && conf > CONF_T) {
                int r = r0 + c0 + tid;
                u32 slot = atomicAdd(&cnt, 1u);
                if (slot < SUBCAP)
                    skey[slot] = ((u64)__float_as_uint(conf) << 32) | (u64)(u32)(~(u32)r);
            }
        }
        __syncthreads();
    }
    // bitonic sort, descending, 512 elements, 512 threads (45 passes)
    for (int k = 2; k <= SUBCAP; k <<= 1) {
        for (int j = k >> 1; j > 0; j >>= 1) {
            int t = tid, p = t ^ j;
            if (p > t) {
                u64 a = skey[t], c2 = skey[p];
                bool desc = ((t & k) == 0);
                if (desc ? (a < c2) : (a > c2)) { skey[t] = c2; skey[p] = a; }
            }
            __syncthreads();
        }
    }
    cand_ws[(size_t)bs * SUBCAP + tid] = skey[tid];
}

// K2: rank, 8 blocks per image. Each block loads the image's full 8x512 key
// set and ranks its own sub-list's 512 keys: rank(key) = sum over all 8 lists
// of count(elements > key); own list's search returns the key's own index
// (keys unique). Breadth-interleaved pow2 ladder: 10 rounds x 8 independent
// LDS probes. Keys with rank < TOPK scatter to tkey_ws[b][rank].
__global__ __launch_bounds__(512) void rank_kernel(const u64* __restrict__ cand_ws,
                                                   u64* __restrict__ tkey_ws) {
    __shared__ u64 lists[SUBS * SUBCAP];   // 32 KB
    int bs = blockIdx.x;          // 0..255
    int b = bs >> 3, s = bs & 7;
    int tid = threadIdx.x;
    const u64* src = cand_ws + (size_t)b * SUBS * SUBCAP;
    for (int t = tid; t < SUBS * SUBCAP; t += 512) lists[t] = src[t];
    __syncthreads();
    u64 key = lists[(s << 9) + tid];
    if (key) {
        int lo[SUBS];
#pragma unroll
        for (int l = 0; l < SUBS; ++l) lo[l] = 0;
#pragma unroll
        for (int w2 = SUBCAP; w2 >= 1; w2 >>= 1) {   // 10 rounds
#pragma unroll
            for (int l = 0; l < SUBS; ++l) {
                int p = lo[l] + w2;
                if (p <= SUBCAP && lists[(l << 9) + p - 1] > key) lo[l] = p;
            }
        }
        int rank = 0;
#pragma unroll
        for (int l = 0; l < SUBS; ++l) rank += lo[l];
        if (rank < TOPK) tkey_ws[(size_t)b * TKROW + rank] = key;
    }
}

// K3: suppression matrix as 136 upper-triangle 64x64 tiles per image,
// one tile per wave (8 blocks/image x 16 waves). Gathers pred rows from
// tkey_ws itself (deterministic recompute; identical FP expressions).
// j is wave-uniform -> LDS broadcast reads; word accumulates in a register.
__global__ __launch_bounds__(1024) void supmat_kernel(const float* __restrict__ pred,
                                                      const u64* __restrict__ tkey_ws,
                                                      u64* __restrict__ sup_g) {
    __shared__ float4 bx_s[TOPK];   // 16 KB
    __shared__ float  ar_s[TOPK];   // 4 KB
    int b = blockIdx.x >> 3, q = blockIdx.x & 7;
    int tid = threadIdx.x;
    if (tid < TOPK) {
        u64 key = tkey_ws[(size_t)b * TKROW + tid];
        float4 box = make_float4(0.f, 0.f, 0.f, 0.f);
        float ar = 0.f;
        if (key) {
            u32 r = ~(u32)key;
            const float* p = pred + ((size_t)b * NPRED + r) * ROWF;
            float x = p[0], y = p[1], w = p[2], hh = p[3];
            box = make_float4(x - w * 0.5f, y - hh * 0.5f, x + w * 0.5f, y + hh * 0.5f);
            ar = (box.z - box.x) * (box.w - box.y);
        }
        bx_s[tid] = box; ar_s[tid] = ar;
    }
    __syncthreads();
    int wave = tid >> 6, lane = tid & 63;
    for (int pass = 0; pass < 2; ++pass) {
        int t = (pass == 0) ? (q * 16 + wave) : ((wave == 15) ? 128 + q : 136);
        if (t >= 136) continue;
        // decode tile t -> (iw, jw), jw >= iw
        int iw = 0, rem = t, c = 16;
        while (rem >= c) { rem -= c; c--; iw++; }
        int jw = iw + rem;
        int i = iw * 64 + lane;
        bool act = i < TOPK;
        float4 bi = act ? bx_s[i] : make_float4(0.f, 0.f, 0.f, 0.f);
        float ai = act ? ar_s[i] : 0.f;
        u64 m = 0;
        int jbase = jw << 6;
        int jend = jbase + 64; if (jend > TOPK) jend = TOPK;
        for (int j = jbase; j < jend; ++j) {
            float4 bj = bx_s[j];            // broadcast
            float aj = ar_s[j];             // broadcast
            float lx = fmaxf(bi.x, bj.x);
            float ly = fmaxf(bi.y, bj.y);
            float rx = fminf(bi.z, bj.z);
            float ry = fminf(bi.w, bj.w);
            float iw2 = rx - lx; iw2 = iw2 > 0.f ? iw2 : 0.f;
            float ih = ry - ly; ih = ih > 0.f ? ih : 0.f;
            float inter = iw2 * ih;
            float den = ai + aj - inter + 1e-7f;  // ((ai+aj)-inter)+eps, ref order
            float iou = inter / den;
            if (act && j > i && iou > IOU_T) m |= 1ull << (j - jbase);
        }
        if (act) sup_g[((size_t)b * KW + jw) * SUPROW + i] = m;
    }
}

// K4: sparse register-resident greedy scan + output. keep0 from key!=0 via
// ballot; score from key bits; pred gathered only for kept rows. Serial loop
// only visits rows that actually suppress (ballot-gated); uniform broadcasts
// via v_readlane (VALU, no LDS pipe in the chain).
__global__ __launch_bounds__(1024) void scan_out_kernel(const float* __restrict__ pred,
                                                        const u64* __restrict__ tkey_ws,
                                                        const u64* __restrict__ sup_g,
                                                        float* __restrict__ out,
                                                        float* __restrict__ keepout) {
    __shared__ u64 keep_lds[KW];
    __shared__ u64 acc_lds;
    int b = blockIdx.x, tid = threadIdx.x;
    int w = tid >> 6, lane = tid & 63;
    const u64* S = sup_g + (size_t)b * KW * SUPROW;

    u64 key = tkey_ws[(size_t)b * TKROW + tid];   // slots >= TOPK are zero
    u64 keep0 = __ballot(key != 0ull);            // row w*64+lane
    if (lane == 0) keep_lds[w] = keep0;

    u64 sup_reg[KW];
    u64 diagreg = 0;
#pragma unroll
    for (int bi = 0; bi < KW; ++bi) {
        sup_reg[bi] = S[(size_t)w * SUPROW + (bi << 6) + lane]; // bi>w: garbage, never used
        if (bi == w) diagreg = sup_reg[bi];
    }
    __syncthreads();

    u64 nzmask = __ballot(diagreg != 0);   // rows of this word with in-word suppression

#pragma unroll
    for (int bi = 0; bi < KW; ++bi) {
        if (w == bi) {
            // serial greedy within word bi; only suppressor rows enter the loop
            u64 cur = keep_lds[bi];
            u64 active = cur & nzmask;
            while (active) {
                int i = __ffsll((long long)active) - 1;
                u64 wi = readlane64(diagreg, i);   // row i's mask (bits > i only)
                active &= active - 1;              // retire bit i
                cur &= ~wi;
                active &= ~wi;                     // suppressed rows can't suppress
            }
            if (lane == 0) { keep_lds[bi] = cur; acc_lds = cur; }
        }
        __syncthreads();
        if (w > bi) {
            u64 A = acc_lds;                       // accepted set of block bi
            u64 myv = sup_reg[bi];                 // row (bi*64+lane)'s mask over word w
            bool accb = (A >> lane) & 1ull;
            u64 lanes = __ballot(accb && myv != 0ull);
            if (lanes) {                           // rare: sparse suppression
                u64 wred = 0;
                while (lanes) {
                    int l = __ffsll((long long)lanes) - 1;
                    wred |= readlane64(myv, l);
                    lanes &= lanes - 1;
                }
                if (lane == 0) keep_lds[w] &= ~wred;
            }
        }
        __syncthreads();
    }

    if (tid < TOPK) {
        bool kp = ((keep_lds[w] >> lane) & 1ull) != 0;
        float o0 = 0.f, o1 = 0.f, o2 = 0.f, o3 = 0.f, o4 = 0.f, o6 = 0.f, o7 = 0.f, o8 = 0.f;
        if (kp) {
            u32 r = ~(u32)key;
            const float* p = pred + ((size_t)b * NPRED + r) * ROWF;
            float x = p[0], y = p[1], wd = p[2], hh = p[3];
            o0 = x - wd * 0.5f; o1 = y - hh * 0.5f;
            o2 = x + wd * 0.5f; o3 = y + hh * 0.5f;
            o4 = __uint_as_float((u32)(key >> 32));
            o6 = p[6]; o7 = p[7]; o8 = p[8];
        }
        size_t ob = ((size_t)b * TOPK + tid) * ROWF;
        out[ob + 0] = o0; out[ob + 1] = o1; out[ob + 2] = o2; out[ob + 3] = o3;
        out[ob + 4] = o4; out[ob + 5] = 0.f;
        out[ob + 6] = o6; out[ob + 7] = o7; out[ob + 8] = o8;
        keepout[(size_t)b * TOPK + tid] = kp ? 1.0f : 0.0f;
    }
}

extern "C" void kernel_launch(void* const* d_in, const int* in_sizes, int n_in,
                              void* d_out, int out_size, void* d_ws, size_t ws_size,
                              hipStream_t stream) {
    const float* pred = (const float*)d_in[0];
    float* out = (float*)d_out;                         // [32,1000,9]
    float* keepout = out + (size_t)BATCH * TOPK * ROWF; // [32,1000]
    char* ws = (char*)d_ws;
    u64* cand_ws = (u64*)(ws + WS_CAND);
    u64* tkey_ws = (u64*)(ws + WS_TKEY);
    u64* sup_g = (u64*)(ws + WS_SUP);

    compact_sort_kernel<<<BATCH * SUBS, 512, 0, stream>>>(pred, cand_ws, tkey_ws);
    rank_kernel<<<BATCH * SUBS, 512, 0, stream>>>(cand_ws, tkey_ws);
    supmat_kernel<<<BATCH * SUBS, 1024, 0, stream>>>(pred, tkey_ws, sup_g);
    scan_out_kernel<<<BATCH, 1024, 0, stream>>>(pred, tkey_ws, sup_g, out, keepout);
}